// Round 2
// baseline (120.268 us; speedup 1.0000x reference)
//
#include <hip/hip_runtime.h>
#include <hip/hip_bf16.h>
#include <stdint.h>

// Problem constants
#define BB 64     // batch
#define LL 256    // x seq len
#define TT 64     // y seq len
#define DD 512    // input dim
#define EE 200    // embed dim
#define EP 224    // embed dim padded to 7*32 for MFMA K
#define YSTRIDE 232  // LDS row stride (shorts): 464 B -> bank step 20 mod 32, ~conflict-free
#define NROWS_X 16384  // 64*256
#define NROWS_ALL 20480  // + 64*64

typedef __attribute__((ext_vector_type(8))) short short8;
typedef __attribute__((ext_vector_type(4))) float floatx4;
typedef __attribute__((ext_vector_type(4))) int intx4;

__device__ __forceinline__ short f2bf(float f) {
  uint32_t u = __builtin_bit_cast(uint32_t, f);
  u = (u + 0x7fffu + ((u >> 16) & 1u)) >> 16;  // RNE
  return (short)u;
}

// ---------------- Kernel 0: W (200x512 f32) -> Wb (224x512 bf16, zero-padded rows)
__global__ void wcvt_kernel(const float* __restrict__ W, short* __restrict__ Wb) {
  int idx = blockIdx.x * 256 + threadIdx.x;   // 0 .. 224*512-1
  int e = idx >> 9;
  int k = idx & 511;
  float v = (e < EE) ? W[e * DD + k] : 0.0f;
  Wb[idx] = f2bf(v);
}

// ---------------- Kernel 1: projection over both x and y (rows 0..20479)
// Block: 256 thr = 4 waves. wave = (rowgrp = wid>>1) x (ehalf = wid&1).
// Block covers 32 rows x 224 cols. Grid 640 -> ~2.5 blocks/CU, high TLP.
__global__ __launch_bounds__(256) void proj_kernel(const float* __restrict__ x,
                                                   const float* __restrict__ y,
                                                   const short* __restrict__ Wb,
                                                   const float* __restrict__ bias,
                                                   short* __restrict__ out) {
  const int tid  = threadIdx.x;
  const int lane = tid & 63;
  const int wid  = tid >> 6;
  const int r16   = lane & 15;
  const int khalf = lane >> 4;          // 0..3
  const int row0 = blockIdx.x * 32 + (wid >> 1) * 16;   // global row of this wave's 16-row tile
  const int eoff = (wid & 1) * 112;                      // E-half

  floatx4 acc[7];
#pragma unroll
  for (int n = 0; n < 7; n++) acc[n] = (floatx4){0.f, 0.f, 0.f, 0.f};

  const float* src = (row0 < NROWS_X)
                       ? (x + (size_t)(row0 + r16) * DD)
                       : (y + (size_t)(row0 - NROWS_X + r16) * DD);
  const float* arow = src + khalf * 8;

  for (int kk = 0; kk < 16; kk++) {     // K = 512 = 16 * 32
    const floatx4* ap = (const floatx4*)(arow + kk * 32);
    floatx4 a0 = ap[0];
    floatx4 a1 = ap[1];
    short8 afrag;
    afrag[0] = f2bf(a0.x); afrag[1] = f2bf(a0.y);
    afrag[2] = f2bf(a0.z); afrag[3] = f2bf(a0.w);
    afrag[4] = f2bf(a1.x); afrag[5] = f2bf(a1.y);
    afrag[6] = f2bf(a1.z); afrag[7] = f2bf(a1.w);
#pragma unroll
    for (int n = 0; n < 7; n++) {
      const short8 wfrag = *(const short8*)(Wb + (size_t)(eoff + n * 16 + r16) * DD + kk * 32 + khalf * 8);
      acc[n] = __builtin_amdgcn_mfma_f32_16x16x32_bf16(afrag, wfrag, acc[n], 0, 0, 0);
    }
  }

  // Epilogue: C/D layout col = lane&15 (e), row = (lane>>4)*4 + reg (input row)
  const int orow = row0 + khalf * 4;
#pragma unroll
  for (int n = 0; n < 7; n++) {
    const int e = eoff + n * 16 + r16;
    const float bv = (e < EE) ? bias[e] : 0.0f;  // pad cols: acc==0, bv==0 -> store 0
#pragma unroll
    for (int r = 0; r < 4; r++) {
      out[(size_t)(orow + r) * EP + e] = f2bf(acc[n][r] + bv);
    }
  }
}

// ---------------- Kernel 2: pair kernel
// Block = (j-pair, group of 4 i). Stage yp[j0],yp[j0+1] in LDS ONCE, then loop
// 4 i's: 4 waves x 64 L-rows x 64 t x 2 j, fused col-max into red[], one final
// barrier + reduce. Grid 32*16 = 512 blocks = 2/CU.
__global__ __launch_bounds__(256) void pair_kernel(const short* __restrict__ xp,
                                                   const short* __restrict__ yp,
                                                   float* __restrict__ S) {
  __shared__ short ylds[2][TT][YSTRIDE];   // 59,392 B
  __shared__ float red[4][4][2][TT];       // [i_local][wid][jj][t] = 8,192 B

  const int tid  = threadIdx.x;
  const int lane = tid & 63;
  const int wid  = tid >> 6;
  const int jpair = blockIdx.x & 31;
  const int igrp  = blockIdx.x >> 5;       // 0..15
  const int j0 = jpair * 2;

  // Stage yp[j0] and yp[j0+1] into LDS (64 rows x 224 shorts each, 16B chunks)
#pragma unroll
  for (int jj = 0; jj < 2; jj++) {
    const intx4* src = (const intx4*)(yp + (size_t)(j0 + jj) * TT * EP);
    for (int c = tid; c < TT * 28; c += 256) {   // 28 = 224/8 shorts per 16B
      int row = c / 28, ch = c % 28;
      *(intx4*)&ylds[jj][row][ch * 8] = src[c];
    }
  }
  __syncthreads();

  const int r16   = lane & 15;
  const int khalf = lane >> 4;

  for (int il = 0; il < 4; il++) {
    const int i = igrp * 4 + il;

    floatx4 acc[2][4][4];
#pragma unroll
    for (int jj = 0; jj < 2; jj++)
#pragma unroll
      for (int m = 0; m < 4; m++)
#pragma unroll
        for (int n = 0; n < 4; n++) acc[jj][m][n] = (floatx4){0.f, 0.f, 0.f, 0.f};

    const short* abase = xp + ((size_t)i * LL + wid * 64 + r16) * EP + khalf * 8;

#pragma unroll
    for (int kk = 0; kk < 7; kk++) {      // K = 224 = 7 * 32
      short8 a[4];
#pragma unroll
      for (int m = 0; m < 4; m++)
        a[m] = *(const short8*)(abase + (size_t)m * 16 * EP + kk * 32);
#pragma unroll
      for (int jj = 0; jj < 2; jj++) {
#pragma unroll
        for (int n = 0; n < 4; n++) {
          const short8 bfrag = *(const short8*)&ylds[jj][n * 16 + r16][kk * 32 + khalf * 8];
#pragma unroll
          for (int m = 0; m < 4; m++)
            acc[jj][m][n] = __builtin_amdgcn_mfma_f32_16x16x32_bf16(a[m], bfrag, acc[jj][m][n], 0, 0, 0);
        }
      }
    }

    // Per-wave max over its 64 L-rows for each column t; no barrier needed here.
    // C layout: col t = n*16 + (lane&15); rows live in (lane>>4)*4 + reg across m.
#pragma unroll
    for (int jj = 0; jj < 2; jj++) {
#pragma unroll
      for (int n = 0; n < 4; n++) {
        float v = acc[jj][0][n][0];
#pragma unroll
        for (int m = 0; m < 4; m++)
#pragma unroll
          for (int r = 0; r < 4; r++) v = fmaxf(v, acc[jj][m][n][r]);
        v = fmaxf(v, __shfl_xor(v, 16, 64));
        v = fmaxf(v, __shfl_xor(v, 32, 64));
        if (lane < 16) red[il][wid][jj][n * 16 + lane] = v;
      }
    }
  }
  __syncthreads();

  // Final: wave `wid` handles i_local = wid; lane = t. Max across 4 waves' partials,
  // then mean over t via shuffle-sum.
  {
    const int il = wid;
    const int t  = lane;
    const int i  = igrp * 4 + il;
#pragma unroll
    for (int jj = 0; jj < 2; jj++) {
      float v = fmaxf(fmaxf(red[il][0][jj][t], red[il][1][jj][t]),
                      fmaxf(red[il][2][jj][t], red[il][3][jj][t]));
      v += __shfl_xor(v, 1, 64);
      v += __shfl_xor(v, 2, 64);
      v += __shfl_xor(v, 4, 64);
      v += __shfl_xor(v, 8, 64);
      v += __shfl_xor(v, 16, 64);
      v += __shfl_xor(v, 32, 64);
      if (t == 0) S[i * BB + j0 + jj] = v * (1.0f / 64.0f);
    }
  }
}

extern "C" void kernel_launch(void* const* d_in, const int* in_sizes, int n_in,
                              void* d_out, int out_size, void* d_ws, size_t ws_size,
                              hipStream_t stream) {
  const float* x = (const float*)d_in[0];   // 64*256*512
  const float* y = (const float*)d_in[1];   // 64*64*512
  const float* W = (const float*)d_in[2];   // 200*512
  const float* b = (const float*)d_in[3];   // 200
  float* S = (float*)d_out;                 // 64*64

  char* ws = (char*)d_ws;
  short* Wb = (short*)ws;                              // 224*512*2   = 229,376 B
  short* xp = (short*)(ws + 262144);                   // 16384*224*2 = 7,340,032 B
  short* yp = (short*)(ws + 262144 + 7340032);         // 4096*224*2  = 1,835,008 B
  // proj writes rows 0..16383 -> xp, 16384..20479 -> yp (contiguous)

  wcvt_kernel<<<448, 256, 0, stream>>>(W, Wb);
  proj_kernel<<<640, 256, 0, stream>>>(x, y, Wb, b, xp);  // 20480 rows, xp||yp
  pair_kernel<<<512, 256, 0, stream>>>(xp, yp, S);
}

// Round 3
// 98.411 us; speedup vs baseline: 1.2221x; 1.2221x over previous
//
#include <hip/hip_runtime.h>
#include <hip/hip_bf16.h>
#include <stdint.h>

// Problem constants
#define BB 64     // batch
#define LL 256    // x seq len
#define TT 64     // y seq len
#define DD 512    // input dim
#define EE 200    // embed dim
#define EP 224    // embed dim padded (MFMA K multiple)
#define YSTRIDE 232  // LDS row stride in shorts (464 B)
#define NROWS_X 16384  // 64*256

typedef __attribute__((ext_vector_type(8))) short short8;
typedef __attribute__((ext_vector_type(4))) float floatx4;
typedef __attribute__((ext_vector_type(16))) float floatx16;
typedef __attribute__((ext_vector_type(4))) int intx4;

__device__ __forceinline__ short f2bf(float f) {
  uint32_t u = __builtin_bit_cast(uint32_t, f);
  u = (u + 0x7fffu + ((u >> 16) & 1u)) >> 16;  // RNE
  return (short)u;
}

// Pack two f32 high-halves (truncating bf16) into one u32 with a single v_perm.
__device__ __forceinline__ uint32_t pack2(float lo, float hi) {
  return __builtin_amdgcn_perm(__builtin_bit_cast(uint32_t, hi),
                               __builtin_bit_cast(uint32_t, lo), 0x07060302u);
}

// ---------------- Kernel 0: W (200x512 f32) -> Wb (224x512 bf16, zero-padded rows)
__global__ void wcvt_kernel(const float* __restrict__ W, short* __restrict__ Wb) {
  int idx = blockIdx.x * 256 + threadIdx.x;   // 0 .. 224*512-1
  int e = idx >> 9;
  int k = idx & 511;
  float v = (e < EE) ? W[e * DD + k] : 0.0f;
  Wb[idx] = f2bf(v);
}

// ---------------- Kernel 1: projection over both x and y (rows 0..20479)
// Block: 256 thr = 4 waves. wave = (rowgrp = wid>>1) x (ehalf = wid&1).
// Block covers 32 rows x 224 cols. Grid 640.
__global__ __launch_bounds__(256) void proj_kernel(const float* __restrict__ x,
                                                   const float* __restrict__ y,
                                                   const short* __restrict__ Wb,
                                                   const float* __restrict__ bias,
                                                   short* __restrict__ out) {
  const int tid  = threadIdx.x;
  const int lane = tid & 63;
  const int wid  = tid >> 6;
  const int r16   = lane & 15;
  const int khalf = lane >> 4;          // 0..3
  const int row0 = blockIdx.x * 32 + (wid >> 1) * 16;
  const int eoff = (wid & 1) * 112;

  floatx4 acc[7];
#pragma unroll
  for (int n = 0; n < 7; n++) acc[n] = (floatx4){0.f, 0.f, 0.f, 0.f};

  const float* src = (row0 < NROWS_X)
                       ? (x + (size_t)(row0 + r16) * DD)
                       : (y + (size_t)(row0 - NROWS_X + r16) * DD);
  const float* arow = src + khalf * 8;

#pragma unroll 4
  for (int kk = 0; kk < 16; kk++) {     // K = 512 = 16 * 32
    const floatx4* ap = (const floatx4*)(arow + kk * 32);
    floatx4 a0 = ap[0];
    floatx4 a1 = ap[1];
    union { short8 s; uint32_t u[4]; } af;
    af.u[0] = pack2(a0.x, a0.y);
    af.u[1] = pack2(a0.z, a0.w);
    af.u[2] = pack2(a1.x, a1.y);
    af.u[3] = pack2(a1.z, a1.w);
#pragma unroll
    for (int n = 0; n < 7; n++) {
      const short8 wfrag = *(const short8*)(Wb + (size_t)(eoff + n * 16 + r16) * DD + kk * 32 + khalf * 8);
      acc[n] = __builtin_amdgcn_mfma_f32_16x16x32_bf16(af.s, wfrag, acc[n], 0, 0, 0);
    }
  }

  // Epilogue: C/D layout col = lane&15 (e), row = (lane>>4)*4 + reg
  const int orow = row0 + khalf * 4;
#pragma unroll
  for (int n = 0; n < 7; n++) {
    const int e = eoff + n * 16 + r16;
    const float bv = (e < EE) ? bias[e] : 0.0f;
#pragma unroll
    for (int r = 0; r < 4; r++) {
      out[(size_t)(orow + r) * EP + e] = f2bf(acc[n][r] + bv);
    }
  }
}

// ---------------- Kernel 2: pair kernel (32x32x16 MFMA)
// Block = 512 thr = 8 waves = (i-pair) x (j-pair). Wave (il = wid>>2, wq = wid&3):
// M = 64 L-rows (wq quarter) x N = 64 t x 2 j, K = 224 = 14*16.
// ylds staged once per block; A from global (L2-resident xp), reused across 2 j in regs.
__global__ __launch_bounds__(512) void pair_kernel(const short* __restrict__ xp,
                                                   const short* __restrict__ yp,
                                                   float* __restrict__ S) {
  __shared__ short ylds[2][TT][YSTRIDE];   // 59,392 B
  __shared__ float red[2][4][2][TT];       // [il][wq][jj][t] = 4,096 B

  const int tid  = threadIdx.x;
  const int lane = tid & 63;
  const int wid  = tid >> 6;         // 0..7
  const int il   = wid >> 2;         // i within pair
  const int wq   = wid & 3;          // L-quarter
  const int ibase = (blockIdx.x >> 5) * 2;
  const int j0    = (blockIdx.x & 31) * 2;

  // Stage yp[j0] and yp[j0+1]: 2*64*28 = 3584 16-B chunks, 512 thr -> 7 iters
  for (int c = tid; c < 2 * TT * 28; c += 512) {
    const int jj  = (c >= TT * 28) ? 1 : 0;
    const int cc  = c - jj * TT * 28;
    const int row = cc / 28, ch = cc % 28;
    *(intx4*)&ylds[jj][row][ch * 8] =
        ((const intx4*)(yp + (size_t)(j0 + jj) * TT * EP))[cc];
  }
  __syncthreads();

  const int r32 = lane & 31;
  const int kh  = lane >> 5;         // 0..1

  floatx16 acc[2][2][2];             // [jj][m][n]
#pragma unroll
  for (int jj = 0; jj < 2; jj++)
#pragma unroll
    for (int m = 0; m < 2; m++)
#pragma unroll
      for (int n = 0; n < 2; n++)
#pragma unroll
        for (int r = 0; r < 16; r++) acc[jj][m][n][r] = 0.f;

  // A layout for 32x32x16: lane holds row = lane&31, k = (lane>>5)*8 + [0..8)
  const short* abase = xp + ((size_t)(ibase + il) * LL + wq * 64 + r32) * EP + kh * 8;

#pragma unroll
  for (int kk = 0; kk < 14; kk++) {  // K = 224 = 14 * 16
    short8 a0 = *(const short8*)(abase + kk * 16);
    short8 a1 = *(const short8*)(abase + (size_t)32 * EP + kk * 16);
#pragma unroll
    for (int jj = 0; jj < 2; jj++) {
#pragma unroll
      for (int n = 0; n < 2; n++) {
        const short8 bfrag = *(const short8*)&ylds[jj][n * 32 + r32][kk * 16 + kh * 8];
        acc[jj][0][n] = __builtin_amdgcn_mfma_f32_32x32x16_bf16(a0, bfrag, acc[jj][0][n], 0, 0, 0);
        acc[jj][1][n] = __builtin_amdgcn_mfma_f32_32x32x16_bf16(a1, bfrag, acc[jj][1][n], 0, 0, 0);
      }
    }
  }

  // Max over this wave's 64 L-rows per column t.
  // C layout 32x32: col = lane&31, row = (reg&3)+8*(reg>>2)+4*(lane>>5) (+m*32)
#pragma unroll
  for (int jj = 0; jj < 2; jj++) {
#pragma unroll
    for (int n = 0; n < 2; n++) {
      float v = acc[jj][0][n][0];
#pragma unroll
      for (int m = 0; m < 2; m++)
#pragma unroll
        for (int r = 0; r < 16; r++) v = fmaxf(v, acc[jj][m][n][r]);
      v = fmaxf(v, __shfl_xor(v, 32, 64));
      if (lane < 32) red[il][wq][jj][n * 32 + lane] = v;
    }
  }
  __syncthreads();

  // Final: waves 0-3 -> (il, jj); lane = t. Max across 4 L-quarters, mean over t.
  if (wid < 4) {
    const int il2 = wid >> 1;
    const int jj  = wid & 1;
    const int t   = lane;
    float v = fmaxf(fmaxf(red[il2][0][jj][t], red[il2][1][jj][t]),
                    fmaxf(red[il2][2][jj][t], red[il2][3][jj][t]));
    v += __shfl_xor(v, 1, 64);
    v += __shfl_xor(v, 2, 64);
    v += __shfl_xor(v, 4, 64);
    v += __shfl_xor(v, 8, 64);
    v += __shfl_xor(v, 16, 64);
    v += __shfl_xor(v, 32, 64);
    if (t == 0) S[(ibase + il2) * BB + j0 + jj] = v * (1.0f / 64.0f);
  }
}

extern "C" void kernel_launch(void* const* d_in, const int* in_sizes, int n_in,
                              void* d_out, int out_size, void* d_ws, size_t ws_size,
                              hipStream_t stream) {
  const float* x = (const float*)d_in[0];   // 64*256*512
  const float* y = (const float*)d_in[1];   // 64*64*512
  const float* W = (const float*)d_in[2];   // 200*512
  const float* b = (const float*)d_in[3];   // 200
  float* S = (float*)d_out;                 // 64*64

  char* ws = (char*)d_ws;
  short* Wb = (short*)ws;                              // 224*512*2   = 229,376 B
  short* xp = (short*)(ws + 262144);                   // 16384*224*2 = 7,340,032 B
  short* yp = (short*)(ws + 262144 + 7340032);         // 4096*224*2  = 1,835,008 B
  // proj writes rows 0..16383 -> xp, 16384..20479 -> yp (contiguous)

  wcvt_kernel<<<448, 256, 0, stream>>>(W, Wb);
  proj_kernel<<<640, 256, 0, stream>>>(x, y, Wb, b, xp);  // 20480 rows, xp||yp
  pair_kernel<<<1024, 512, 0, stream>>>(xp, yp, S);       // 32 ipairs x 32 jpairs
}

// Round 4
// 67.541 us; speedup vs baseline: 1.7807x; 1.4571x over previous
//
#include <hip/hip_runtime.h>
#include <hip/hip_bf16.h>
#include <stdint.h>

// Problem constants
#define BB 64     // batch
#define LL 256    // x seq len
#define TT 64     // y seq len
#define DD 512    // input dim
#define EE 200    // embed dim
#define EP 224    // embed dim padded (MFMA K multiple)
#define YSTRIDE 232  // LDS row stride in shorts (464 B)
#define NROWS_X 16384  // 64*256

typedef __attribute__((ext_vector_type(8))) short short8;
typedef __attribute__((ext_vector_type(4))) float floatx4;
typedef __attribute__((ext_vector_type(16))) float floatx16;
typedef __attribute__((ext_vector_type(4))) int intx4;

__device__ __forceinline__ short f2bf(float f) {
  uint32_t u = __builtin_bit_cast(uint32_t, f);
  u = (u + 0x7fffu + ((u >> 16) & 1u)) >> 16;  // RNE
  return (short)u;
}

// Pack two f32 high-halves (truncating bf16) into one u32 with a single v_perm.
__device__ __forceinline__ uint32_t pack2(float lo, float hi) {
  return __builtin_amdgcn_perm(__builtin_bit_cast(uint32_t, hi),
                               __builtin_bit_cast(uint32_t, lo), 0x07060302u);
}

typedef const __attribute__((address_space(1))) uint32_t gu32_t;
typedef __attribute__((address_space(3))) uint32_t lu32_t;
__device__ __forceinline__ void glds16(const void* g, void* l) {
  __builtin_amdgcn_global_load_lds((gu32_t*)g, (lu32_t*)l, 16, 0, 0);
}

// ---------------- Kernel 0: W (200x512 f32) -> Wb (224x512 bf16, zero-padded rows)
__global__ void wcvt_kernel(const float* __restrict__ W, short* __restrict__ Wb) {
  int idx = blockIdx.x * 256 + threadIdx.x;   // 0 .. 224*512-1
  int e = idx >> 9;
  int k = idx & 511;
  float v = (e < EE) ? W[e * DD + k] : 0.0f;
  Wb[idx] = f2bf(v);
}

// ---------------- Kernel 1: projection GEMM, LDS-staged via global_load_lds
// M=20480 (x rows then y rows), N=224 (E, padded), K=512.
// Block: 256 thr = 4 waves in 2x2 (wm = M-half of 64-row tile, wn = E-half).
// BM=64, BN=224, BK=32, double-buffered. LDS 48 KB -> 3 blocks/CU.
// A is f32 (converted to bf16 at LDS-read time via v_perm); B is bf16 Wb.
// Source-side XOR swizzle (LDS linear, glds dest = lane-linear), same XOR on read.
__global__ __launch_bounds__(256, 3) void proj_kernel(const float* __restrict__ x,
                                                      const float* __restrict__ y,
                                                      const short* __restrict__ Wb,
                                                      const float* __restrict__ bias,
                                                      short* __restrict__ out) {
  __shared__ float ldsA[2][64 * 32];    // [buf][row*32 + k]   8 KB per buf
  __shared__ short ldsB[2][256 * 32];   // [buf][erow*32 + k] 16 KB per buf (rows 224-255 pad)

  const int tid  = threadIdx.x;
  const int lane = tid & 63;
  const int wid  = tid >> 6;
  const int wm = wid >> 1;            // M-half (32 rows)
  const int wn = wid & 1;             // E-half (112 cols)
  const int r16   = lane & 15;
  const int khalf = lane >> 4;        // 0..3

  const int row0 = blockIdx.x * 64;
  const float* srcbase = (blockIdx.x < 256) ? (x + (size_t)row0 * DD)
                                            : (y + (size_t)(row0 - NROWS_X) * DD);

  floatx4 acc[2][7];
#pragma unroll
  for (int mt = 0; mt < 2; mt++)
#pragma unroll
    for (int n = 0; n < 7; n++) acc[mt][n] = (floatx4){0.f, 0.f, 0.f, 0.f};

  // Stage K-step ks into buffer buf. A: 512 16B-chunks (2 issues); B: 1024 (4 issues).
  // A content: ldsA[r][c] = x[r][kbase + (c^(r&7))*4 .. +4)   (c = 16B chunk idx, 8/row)
  // B content: ldsB[r][c] = Wb[r][kbase + (c^(r&3))*8 .. +8)  (c = 16B chunk idx, 4/row)
  auto stage = [&](int buf, int ks) {
#pragma unroll
    for (int i = 0; i < 2; i++) {
      const int p = i * 256 + tid;
      const int r = p >> 3, c = p & 7;
      const float* g = srcbase + (size_t)r * DD + ks * 32 + ((c ^ (r & 7)) << 2);
      glds16(g, &ldsA[buf][p * 4]);
    }
#pragma unroll
    for (int i = 0; i < 4; i++) {
      const int p = i * 256 + tid;
      const int r = p >> 2, c = p & 3;
      const int sr = (r < EP) ? r : 0;   // pad rows: load row 0 (never read)
      const short* g = Wb + (size_t)sr * DD + ks * 32 + ((c ^ (r & 3)) << 3);
      glds16(g, &ldsB[buf][p * 8]);
    }
  };

  stage(0, 0);

  for (int s = 0; s < 16; s++) {
    __syncthreads();                     // stage(s) complete; prev ds_reads drained
    if (s + 1 < 16) stage((s + 1) & 1, s + 1);

    const int buf = s & 1;
    short8 b[7];
#pragma unroll
    for (int n = 0; n < 7; n++) {
      const int row = wn * 112 + n * 16 + r16;
      b[n] = *(const short8*)&ldsB[buf][row * 32 + ((khalf ^ (row & 3)) << 3)];
    }
    short8 a[2];
#pragma unroll
    for (int mt = 0; mt < 2; mt++) {
      const int r = wm * 32 + mt * 16 + r16;
      const int c0 = (2 * khalf) ^ (r & 7);
      const int c1 = (2 * khalf + 1) ^ (r & 7);
      const floatx4 f0 = *(const floatx4*)&ldsA[buf][r * 32 + c0 * 4];
      const floatx4 f1 = *(const floatx4*)&ldsA[buf][r * 32 + c1 * 4];
      union { short8 s8; uint32_t u[4]; } af;
      af.u[0] = pack2(f0.x, f0.y);
      af.u[1] = pack2(f0.z, f0.w);
      af.u[2] = pack2(f1.x, f1.y);
      af.u[3] = pack2(f1.z, f1.w);
      a[mt] = af.s8;
    }
#pragma unroll
    for (int mt = 0; mt < 2; mt++)
#pragma unroll
      for (int n = 0; n < 7; n++)
        acc[mt][n] = __builtin_amdgcn_mfma_f32_16x16x32_bf16(a[mt], b[n], acc[mt][n], 0, 0, 0);
  }

  // Epilogue: C/D layout col = lane&15 (e-in-tile), row = khalf*4 + reg
  const int orow0 = row0 + wm * 32;
#pragma unroll
  for (int mt = 0; mt < 2; mt++) {
#pragma unroll
    for (int n = 0; n < 7; n++) {
      const int e = wn * 112 + n * 16 + r16;
      const float bv = (e < EE) ? bias[e] : 0.0f;
#pragma unroll
      for (int r = 0; r < 4; r++) {
        out[(size_t)(orow0 + mt * 16 + khalf * 4 + r) * EP + e] = f2bf(acc[mt][n][r] + bv);
      }
    }
  }
}

// ---------------- Kernel 2: pair kernel (32x32x16 MFMA) — unchanged from R3
__global__ __launch_bounds__(512) void pair_kernel(const short* __restrict__ xp,
                                                   const short* __restrict__ yp,
                                                   float* __restrict__ S) {
  __shared__ short ylds[2][TT][YSTRIDE];   // 59,392 B
  __shared__ float red[2][4][2][TT];       // [il][wq][jj][t] = 4,096 B

  const int tid  = threadIdx.x;
  const int lane = tid & 63;
  const int wid  = tid >> 6;         // 0..7
  const int il   = wid >> 2;         // i within pair
  const int wq   = wid & 3;          // L-quarter
  const int ibase = (blockIdx.x >> 5) * 2;
  const int j0    = (blockIdx.x & 31) * 2;

  for (int c = tid; c < 2 * TT * 28; c += 512) {
    const int jj  = (c >= TT * 28) ? 1 : 0;
    const int cc  = c - jj * TT * 28;
    const int row = cc / 28, ch = cc % 28;
    *(intx4*)&ylds[jj][row][ch * 8] =
        ((const intx4*)(yp + (size_t)(j0 + jj) * TT * EP))[cc];
  }
  __syncthreads();

  const int r32 = lane & 31;
  const int kh  = lane >> 5;         // 0..1

  floatx16 acc[2][2][2];             // [jj][m][n]
#pragma unroll
  for (int jj = 0; jj < 2; jj++)
#pragma unroll
    for (int m = 0; m < 2; m++)
#pragma unroll
      for (int n = 0; n < 2; n++)
#pragma unroll
        for (int r = 0; r < 16; r++) acc[jj][m][n][r] = 0.f;

  const short* abase = xp + ((size_t)(ibase + il) * LL + wq * 64 + r32) * EP + kh * 8;

#pragma unroll
  for (int kk = 0; kk < 14; kk++) {  // K = 224 = 14 * 16
    short8 a0 = *(const short8*)(abase + kk * 16);
    short8 a1 = *(const short8*)(abase + (size_t)32 * EP + kk * 16);
#pragma unroll
    for (int jj = 0; jj < 2; jj++) {
#pragma unroll
      for (int n = 0; n < 2; n++) {
        const short8 bfrag = *(const short8*)&ylds[jj][n * 32 + r32][kk * 16 + kh * 8];
        acc[jj][0][n] = __builtin_amdgcn_mfma_f32_32x32x16_bf16(a0, bfrag, acc[jj][0][n], 0, 0, 0);
        acc[jj][1][n] = __builtin_amdgcn_mfma_f32_32x32x16_bf16(a1, bfrag, acc[jj][1][n], 0, 0, 0);
      }
    }
  }

  // Max over this wave's 64 L-rows per column t.
#pragma unroll
  for (int jj = 0; jj < 2; jj++) {
#pragma unroll
    for (int n = 0; n < 2; n++) {
      float v = acc[jj][0][n][0];
#pragma unroll
      for (int m = 0; m < 2; m++)
#pragma unroll
        for (int r = 0; r < 16; r++) v = fmaxf(v, acc[jj][m][n][r]);
      v = fmaxf(v, __shfl_xor(v, 32, 64));
      if (lane < 32) red[il][wq][jj][n * 32 + lane] = v;
    }
  }
  __syncthreads();

  if (wid < 4) {
    const int il2 = wid >> 1;
    const int jj  = wid & 1;
    const int t   = lane;
    float v = fmaxf(fmaxf(red[il2][0][jj][t], red[il2][1][jj][t]),
                    fmaxf(red[il2][2][jj][t], red[il2][3][jj][t]));
    v += __shfl_xor(v, 1, 64);
    v += __shfl_xor(v, 2, 64);
    v += __shfl_xor(v, 4, 64);
    v += __shfl_xor(v, 8, 64);
    v += __shfl_xor(v, 16, 64);
    v += __shfl_xor(v, 32, 64);
    if (t == 0) S[(ibase + il2) * BB + j0 + jj] = v * (1.0f / 64.0f);
  }
}

extern "C" void kernel_launch(void* const* d_in, const int* in_sizes, int n_in,
                              void* d_out, int out_size, void* d_ws, size_t ws_size,
                              hipStream_t stream) {
  const float* x = (const float*)d_in[0];   // 64*256*512
  const float* y = (const float*)d_in[1];   // 64*64*512
  const float* W = (const float*)d_in[2];   // 200*512
  const float* b = (const float*)d_in[3];   // 200
  float* S = (float*)d_out;                 // 64*64

  char* ws = (char*)d_ws;
  short* Wb = (short*)ws;                              // 224*512*2   = 229,376 B
  short* xp = (short*)(ws + 262144);                   // 16384*224*2 = 7,340,032 B
  short* yp = (short*)(ws + 262144 + 7340032);         // 4096*224*2  = 1,835,008 B
  // proj writes rows 0..16383 -> xp, 16384..20479 -> yp (contiguous)

  wcvt_kernel<<<448, 256, 0, stream>>>(W, Wb);
  proj_kernel<<<320, 256, 0, stream>>>(x, y, Wb, b, xp);  // 20480 rows, xp||yp
  pair_kernel<<<1024, 512, 0, stream>>>(xp, yp, S);       // 32 ipairs x 32 jpairs
}

// Round 5
// 61.703 us; speedup vs baseline: 1.9491x; 1.0946x over previous
//
#include <hip/hip_runtime.h>
#include <hip/hip_bf16.h>
#include <stdint.h>

// Problem constants
#define BB 64      // batch
#define LL 256     // x seq len
#define TT 64      // y seq len
#define DD 512     // input dim
#define EE 200     // embed dim
#define EP 208     // embed dim padded to 13*16 (32x32x16 MFMA K-granularity)
#define NKK 13     // K-steps in pair kernel (EP/16)
#define NROWS_X 16384   // 64*256
// Fragment-chunk layout: 1 chunk = 32 rows x 16 e = 64 lanes x 16 B = 1024 B.
// lane l holds row (l&31), e_local (l>>5)*8 .. +8, at byte l*16 within chunk.
// xpT chunk index: (i*8 + lt)*13 + kk      (lt = L-tile 0..7)
// ypT chunk index: (j*2 + nt)*13 + kk      (nt = T-tile 0..1)
#define YCH_PER_J (2 * NKK * 64)  // 16B-units per j slice = 1664

typedef __attribute__((ext_vector_type(8))) short short8;
typedef __attribute__((ext_vector_type(4))) float floatx4;
typedef __attribute__((ext_vector_type(16))) float floatx16;

__device__ __forceinline__ short f2bf(float f) {
  uint32_t u = __builtin_bit_cast(uint32_t, f);
  u = (u + 0x7fffu + ((u >> 16) & 1u)) >> 16;  // RNE
  return (short)u;
}

// Pack two f32 (truncating to bf16) into one u32 with a single v_perm.
__device__ __forceinline__ uint32_t pack2(float lo, float hi) {
  return __builtin_amdgcn_perm(__builtin_bit_cast(uint32_t, hi),
                               __builtin_bit_cast(uint32_t, lo), 0x07060302u);
}

typedef const __attribute__((address_space(1))) uint32_t gu32_t;
typedef __attribute__((address_space(3))) uint32_t lu32_t;
__device__ __forceinline__ void glds16(const void* g, void* l) {
  __builtin_amdgcn_global_load_lds((gu32_t*)g, (lu32_t*)l, 16, 0, 0);
}

// ---------------- Kernel 0: W (200x512 f32) -> Wb (208x512 bf16, zero-padded rows)
__global__ void wcvt_kernel(const float* __restrict__ W, short* __restrict__ Wb) {
  int idx = blockIdx.x * 256 + threadIdx.x;   // 0 .. 208*512-1
  int e = idx >> 9;
  int k = idx & 511;
  float v = (e < EE) ? W[e * DD + k] : 0.0f;
  Wb[idx] = f2bf(v);
}

// ---------------- Kernel 1: projection GEMM -> fragment-layout xpT / ypT
// M=20480 rows (x then y), N=208 (E), K=512. Block: 256 thr = 4 waves,
// wave = 16 rows x 208 E (13 x 16x16x32 MFMA). BM=64, BK=32, double-buffered
// via global_load_lds, source-side XOR swizzle, LDS linear. 43KB -> 3 blocks/CU.
__global__ __launch_bounds__(256, 3) void proj_kernel(const float* __restrict__ x,
                                                      const float* __restrict__ y,
                                                      const short* __restrict__ Wb,
                                                      const float* __restrict__ bias,
                                                      short* __restrict__ xpT,
                                                      short* __restrict__ ypT) {
  __shared__ float ldsA[2][64 * 32];    // [buf][r*32 + k]   8 KB per buf
  __shared__ short ldsB[2][208 * 32];   // [buf][e*32 + k]  13 KB per buf

  const int tid  = threadIdx.x;
  const int lane = tid & 63;
  const int wid  = tid >> 6;
  const int r16   = lane & 15;
  const int khalf = lane >> 4;        // 0..3

  const int row0 = blockIdx.x * 64;
  const float* srcbase = (row0 < NROWS_X) ? (x + (size_t)row0 * DD)
                                          : (y + (size_t)(row0 - NROWS_X) * DD);

  floatx4 acc[NKK];
#pragma unroll
  for (int n = 0; n < NKK; n++) acc[n] = (floatx4){0.f, 0.f, 0.f, 0.f};

  // Stage K-step ks. A: 512 16B-chunks; B: 832 16B-chunks.
  // ldsA[r][c16] <- x[r][ks*32 + (c^(r&7))*4 ..+4)
  // ldsB[e][c16] <- Wb[e][ks*32 + (c^(e&3))*8 ..+8)
  auto stage = [&](int buf, int ks) {
#pragma unroll
    for (int it = 0; it < 2; it++) {
      const int p = it * 256 + tid;
      const int r = p >> 3, c = p & 7;
      glds16(srcbase + (size_t)r * DD + ks * 32 + ((c ^ (r & 7)) << 2),
             &ldsA[buf][p * 4]);
    }
#pragma unroll
    for (int it = 0; it < 4; it++) {
      const int p = it * 256 + tid;
      if (p < 832) {
        const int r = p >> 2, c = p & 3;
        glds16(Wb + (size_t)r * DD + ks * 32 + ((c ^ (r & 3)) << 3),
               &ldsB[buf][p * 8]);
      }
    }
  };

  stage(0, 0);

  for (int s = 0; s < 16; s++) {
    __syncthreads();
    if (s + 1 < 16) stage((s + 1) & 1, s + 1);

    const int buf = s & 1;
    const int r = wid * 16 + r16;
    const int c0 = (2 * khalf) ^ (r & 7);
    const int c1 = (2 * khalf + 1) ^ (r & 7);
    const floatx4 f0 = *(const floatx4*)&ldsA[buf][r * 32 + c0 * 4];
    const floatx4 f1 = *(const floatx4*)&ldsA[buf][r * 32 + c1 * 4];
    union { short8 s8; uint32_t u[4]; } af;
    af.u[0] = pack2(f0.x, f0.y);
    af.u[1] = pack2(f0.z, f0.w);
    af.u[2] = pack2(f1.x, f1.y);
    af.u[3] = pack2(f1.z, f1.w);
#pragma unroll
    for (int n = 0; n < NKK; n++) {
      const int erow = n * 16 + r16;
      const short8 bfrag = *(const short8*)&ldsB[buf][erow * 32 + ((khalf ^ (erow & 3)) << 3)];
      acc[n] = __builtin_amdgcn_mfma_f32_16x16x32_bf16(af.s8, bfrag, acc[n], 0, 0, 0);
    }
  }

  // Epilogue: C/D 16x16 layout: e = n*16 + r16, local row = khalf*4 + rr.
  // Write into fragment-chunk layout.
#pragma unroll
  for (int n = 0; n < NKK; n++) {
    const int e = n * 16 + r16;
    const float bv = (e < EE) ? bias[e] : 0.0f;
#pragma unroll
    for (int rr = 0; rr < 4; rr++) {
      const int gr = row0 + wid * 16 + khalf * 4 + rr;
      short* dst;
      int chunk;
      if (gr < NROWS_X) {
        dst = xpT;
        chunk = ((gr >> 8) * 8 + ((gr >> 5) & 7)) * NKK + n;
      } else {
        const int g = gr - NROWS_X;
        dst = ypT;
        chunk = ((g >> 6) * 2 + ((g >> 5) & 1)) * NKK + n;
      }
      dst[(size_t)chunk * 512 + (r16 >> 3) * 256 + (gr & 31) * 8 + (r16 & 7)] =
          f2bf(acc[n][rr] + bv);
    }
  }
}

// ---------------- Kernel 2: pair kernel (32x32x16 MFMA, fragment layouts)
// Block = 512 thr = 8 waves = (il = wid>>2) x (wq = wid&3 L-quarter).
// ylds = yp[j0..j0+1] in fragment layout, staged via global_load_lds (identical
// layouts -> linear both sides). LDS 53,248 B (red aliased) -> 3 blocks/CU.
__global__ __launch_bounds__(512) void pair_kernel(const short* __restrict__ xpT,
                                                   const short* __restrict__ ypT,
                                                   float* __restrict__ S) {
  __shared__ __align__(16) char ldsbuf[53248];
  short* ylds = (short*)ldsbuf;   // [jj][nt][kk][512 shorts]
  float* red  = (float*)ldsbuf;   // [il][wq][jj][64 t] after barrier

  const int tid  = threadIdx.x;
  const int lane = tid & 63;
  const int wid  = tid >> 6;         // 0..7
  const int il   = wid >> 2;
  const int wq   = wid & 3;
  const int ibase = (blockIdx.x >> 5) * 2;
  const int j0    = (blockIdx.x & 31) * 2;

  // Stage 2 j-slices: 2*1664 = 3328 16B-units. Last iter: waves 0-3 only (uniform).
  for (int c = tid; c < 2 * YCH_PER_J; c += 512) {
    const int jj = (c >= YCH_PER_J) ? 1 : 0;
    const int cc = c - jj * YCH_PER_J;
    glds16(ypT + ((size_t)(j0 + jj) * YCH_PER_J + cc) * 8, ldsbuf + c * 16);
  }
  __syncthreads();

  floatx16 acc[2][2][2];             // [jj][m][nt]
#pragma unroll
  for (int jj = 0; jj < 2; jj++)
#pragma unroll
    for (int m = 0; m < 2; m++)
#pragma unroll
      for (int nt = 0; nt < 2; nt++)
#pragma unroll
        for (int r = 0; r < 16; r++) acc[jj][m][nt][r] = 0.f;

  // A chunks for this wave: L-tiles lt = wq*2 + m of row-block i = ibase+il.
  const short* a0base = xpT + ((size_t)(((ibase + il) * 8 + wq * 2 + 0) * NKK) * 512) + lane * 8;
  const short* a1base = xpT + ((size_t)(((ibase + il) * 8 + wq * 2 + 1) * NKK) * 512) + lane * 8;

#pragma unroll
  for (int kk = 0; kk < NKK; kk++) {
    const short8 a0 = *(const short8*)(a0base + kk * 512);
    const short8 a1 = *(const short8*)(a1base + kk * 512);
#pragma unroll
    for (int jj = 0; jj < 2; jj++) {
#pragma unroll
      for (int nt = 0; nt < 2; nt++) {
        const short8 bf = *(const short8*)(ylds + ((jj * 2 + nt) * NKK + kk) * 512 + lane * 8);
        acc[jj][0][nt] = __builtin_amdgcn_mfma_f32_32x32x16_bf16(a0, bf, acc[jj][0][nt], 0, 0, 0);
        acc[jj][1][nt] = __builtin_amdgcn_mfma_f32_32x32x16_bf16(a1, bf, acc[jj][1][nt], 0, 0, 0);
      }
    }
  }

  // Per-wave max over its 64 L-rows per column t (C layout: col = lane&31).
  float vmax[2][2];
#pragma unroll
  for (int jj = 0; jj < 2; jj++) {
#pragma unroll
    for (int nt = 0; nt < 2; nt++) {
      float v = acc[jj][0][nt][0];
#pragma unroll
      for (int m = 0; m < 2; m++)
#pragma unroll
        for (int r = 0; r < 16; r++) v = fmaxf(v, acc[jj][m][nt][r]);
      v = fmaxf(v, __shfl_xor(v, 32, 64));
      vmax[jj][nt] = v;
    }
  }

  __syncthreads();   // all ylds reads done; safe to alias red
  if (lane < 32) {
#pragma unroll
    for (int jj = 0; jj < 2; jj++)
#pragma unroll
      for (int nt = 0; nt < 2; nt++)
        red[(((il * 4 + wq) * 2 + jj) * 64) + nt * 32 + lane] = vmax[jj][nt];
  }
  __syncthreads();

  // Final: waves 0-3 -> (il2, jj); lane = t. Max across 4 L-quarters, mean over t.
  if (wid < 4) {
    const int il2 = wid >> 1;
    const int jj  = wid & 1;
    const int t   = lane;
    float v = red[(((il2 * 4 + 0) * 2 + jj) * 64) + t];
    v = fmaxf(v, red[(((il2 * 4 + 1) * 2 + jj) * 64) + t]);
    v = fmaxf(v, red[(((il2 * 4 + 2) * 2 + jj) * 64) + t]);
    v = fmaxf(v, red[(((il2 * 4 + 3) * 2 + jj) * 64) + t]);
    v += __shfl_xor(v, 1, 64);
    v += __shfl_xor(v, 2, 64);
    v += __shfl_xor(v, 4, 64);
    v += __shfl_xor(v, 8, 64);
    v += __shfl_xor(v, 16, 64);
    v += __shfl_xor(v, 32, 64);
    if (t == 0) S[(ibase + il2) * BB + j0 + jj] = v * (1.0f / 64.0f);
  }
}

extern "C" void kernel_launch(void* const* d_in, const int* in_sizes, int n_in,
                              void* d_out, int out_size, void* d_ws, size_t ws_size,
                              hipStream_t stream) {
  const float* x = (const float*)d_in[0];   // 64*256*512
  const float* y = (const float*)d_in[1];   // 64*64*512
  const float* W = (const float*)d_in[2];   // 200*512
  const float* b = (const float*)d_in[3];   // 200
  float* S = (float*)d_out;                 // 64*64

  char* ws = (char*)d_ws;
  short* Wb  = (short*)ws;                         // 208*512*2 = 212,992 B
  short* xpT = (short*)(ws + 262144);              // 64*8*13*1024 = 6,815,744 B
  short* ypT = (short*)(ws + 262144 + 6815744);    // 64*2*13*1024 = 1,703,936 B

  wcvt_kernel<<<416, 256, 0, stream>>>(W, Wb);
  proj_kernel<<<320, 256, 0, stream>>>(x, y, Wb, b, xpT, ypT);
  pair_kernel<<<1024, 512, 0, stream>>>(xpT, ypT, S);
}

// Round 6
// 48.941 us; speedup vs baseline: 2.4574x; 1.2608x over previous
//
#include <hip/hip_runtime.h>
#include <hip/hip_bf16.h>
#include <stdint.h>

// Problem constants
#define BB 64      // batch
#define LL 256     // x seq len
#define TT 64      // y seq len
#define DD 512     // input dim
#define EE 200     // embed dim
#define EP 208     // embed dim padded to 13*16 (32x32x16 MFMA K-granularity)
#define NKK 13     // K-steps in pair kernel (EP/16)
#define NROWS_X 16384   // 64*256
// Fragment-chunk layout: 1 chunk = 32 rows x 16 e = 64 lanes x 16 B = 1024 B.
// lane l holds row (l&31), e_local (l>>5)*8 .. +8, at shorts chunk*512 + l*8.
// Unified pT: chunk index = (global_row >> 5)*13 + n   (x rows 0..16383, then y).
// ypT starts at chunk 6656 ( = (16384>>5)*13 ).
#define YCH_PER_J (2 * NKK * 64)   // 16B-units per j slice = 1664
#define BSTRIDE 264                // proj bounce row stride in shorts

typedef __attribute__((ext_vector_type(8))) short short8;
typedef __attribute__((ext_vector_type(4))) float floatx4;
typedef __attribute__((ext_vector_type(16))) float floatx16;
typedef __attribute__((ext_vector_type(4))) int intx4;

__device__ __forceinline__ short f2bf(float f) {
  uint32_t u = __builtin_bit_cast(uint32_t, f);
  u = (u + 0x7fffu + ((u >> 16) & 1u)) >> 16;  // RNE
  return (short)u;
}

// Pack two f32 (truncating to bf16) into one u32 with a single v_perm.
__device__ __forceinline__ uint32_t pack2(float lo, float hi) {
  return __builtin_amdgcn_perm(__builtin_bit_cast(uint32_t, hi),
                               __builtin_bit_cast(uint32_t, lo), 0x07060302u);
}

typedef const __attribute__((address_space(1))) uint32_t gu32_t;
typedef __attribute__((address_space(3))) uint32_t lu32_t;
__device__ __forceinline__ void glds16(const void* g, void* l) {
  __builtin_amdgcn_global_load_lds((gu32_t*)g, (lu32_t*)l, 16, 0, 0);
}

// ---------------- Kernel 0: W (200x512 f32) -> Wb (208x512 bf16, zero-padded rows)
__global__ void wcvt_kernel(const float* __restrict__ W, short* __restrict__ Wb) {
  int idx = blockIdx.x * 256 + threadIdx.x;   // 0 .. 208*512-1
  int e = idx >> 9;
  int k = idx & 511;
  float v = (e < EE) ? W[e * DD + k] : 0.0f;
  Wb[idx] = f2bf(v);
}

// ---------------- Kernel 1: projection GEMM -> fragment-layout pT
// M=20480 rows (x then y), N=208 (E), K=512. 256 thr = 4 waves, wave = 16 rows
// x 208 E. BM=64, BK=32, double-buffered global_load_lds. Epilogue: LDS bounce
// -> 16B coalesced fragment stores.
__global__ __launch_bounds__(256, 3) void proj_kernel(const float* __restrict__ x,
                                                      const float* __restrict__ y,
                                                      const short* __restrict__ Wb,
                                                      const float* __restrict__ bias,
                                                      short* __restrict__ pT) {
  __shared__ __align__(16) char smem[43008];
  float* ldsA = (float*)smem;              // [2][64*32]  16,384 B
  short* ldsB = (short*)(smem + 16384);    // [2][208*32] 26,624 B
  short* bounce = (short*)smem;            // [64][BSTRIDE] 33,792 B (after loop)

  const int tid  = threadIdx.x;
  const int lane = tid & 63;
  const int wid  = tid >> 6;
  const int r16   = lane & 15;
  const int khalf = lane >> 4;        // 0..3

  const int row0 = blockIdx.x * 64;
  const float* srcbase = (row0 < NROWS_X) ? (x + (size_t)row0 * DD)
                                          : (y + (size_t)(row0 - NROWS_X) * DD);

  floatx4 acc[NKK];
#pragma unroll
  for (int n = 0; n < NKK; n++) acc[n] = (floatx4){0.f, 0.f, 0.f, 0.f};

  // Stage K-step ks. ldsA[r][c16] <- x[r][ks*32 + (c^(r&7))*4 ..+4)
  //                  ldsB[e][c16] <- Wb[e][ks*32 + (c^(e&3))*8 ..+8)
  auto stage = [&](int buf, int ks) {
#pragma unroll
    for (int it = 0; it < 2; it++) {
      const int p = it * 256 + tid;
      const int r = p >> 3, c = p & 7;
      glds16(srcbase + (size_t)r * DD + ks * 32 + ((c ^ (r & 7)) << 2),
             &ldsA[buf * 2048 + p * 4]);
    }
#pragma unroll
    for (int it = 0; it < 4; it++) {
      const int p = it * 256 + tid;
      if (p < 832) {
        const int r = p >> 2, c = p & 3;
        glds16(Wb + (size_t)r * DD + ks * 32 + ((c ^ (r & 3)) << 3),
               &ldsB[buf * 6656 + p * 8]);
      }
    }
  };

  stage(0, 0);

  for (int s = 0; s < 16; s++) {
    __syncthreads();
    if (s + 1 < 16) stage((s + 1) & 1, s + 1);

    const int buf = s & 1;
    const int r = wid * 16 + r16;
    const int c0 = (2 * khalf) ^ (r & 7);
    const int c1 = (2 * khalf + 1) ^ (r & 7);
    const floatx4 f0 = *(const floatx4*)&ldsA[buf * 2048 + r * 32 + c0 * 4];
    const floatx4 f1 = *(const floatx4*)&ldsA[buf * 2048 + r * 32 + c1 * 4];
    union { short8 s8; uint32_t u[4]; } af;
    af.u[0] = pack2(f0.x, f0.y);
    af.u[1] = pack2(f0.z, f0.w);
    af.u[2] = pack2(f1.x, f1.y);
    af.u[3] = pack2(f1.z, f1.w);
#pragma unroll
    for (int n = 0; n < NKK; n++) {
      const int erow = n * 16 + r16;
      const short8 bfrag = *(const short8*)&ldsB[buf * 6656 + erow * 32 + ((khalf ^ (erow & 3)) << 3)];
      acc[n] = __builtin_amdgcn_mfma_f32_16x16x32_bf16(af.s8, bfrag, acc[n], 0, 0, 0);
    }
  }

  __syncthreads();   // all LDS reads done; safe to reuse smem as bounce

  // Epilogue 1: bias + f2bf -> bounce[lr][e]  (lr = local row, e = embed)
#pragma unroll
  for (int n = 0; n < NKK; n++) {
    const int e = n * 16 + r16;
    const float bv = (e < EE) ? bias[e] : 0.0f;
#pragma unroll
    for (int rr = 0; rr < 4; rr++) {
      const int lr = wid * 16 + khalf * 4 + rr;
      bounce[lr * BSTRIDE + e] = f2bf(acc[n][rr] + bv);
    }
  }
  __syncthreads();

  // Epilogue 2: read fragment pieces (16B) and store coalesced.
  // Piece c (0..1663): q = c>>6 -> (mt = q>=13, n = q-13*mt); l = c&63.
  const int rowblk0 = row0 >> 5;   // global 32-row block index base
  for (int c = tid; c < 1664; c += 256) {
    const int q  = c >> 6;
    const int mt = (q >= 13) ? 1 : 0;
    const int n  = q - mt * 13;
    const int l  = c & 63;
    const int lr = mt * 32 + (l & 31);
    const short8 piece = *(const short8*)&bounce[lr * BSTRIDE + n * 16 + (l >> 5) * 8];
    *(short8*)&pT[((size_t)((rowblk0 + mt) * 13 + n)) * 512 + l * 8] = piece;
  }
}

// ---------------- Kernel 2: pair kernel, Bi=4 x Bj=4, grid 256 = 1 block/CU
// 512 thr = 8 waves: wq = wid&3 (L-quarter), jh = wid>>2 (j-half).
// ylds = 4 full j slices (106,496 B) staged once; red 16,384 B. Loop ii 0..3.
__global__ __launch_bounds__(512, 2) void pair_kernel(const short* __restrict__ xpT,
                                                      const short* __restrict__ ypT,
                                                      float* __restrict__ S) {
  __shared__ __align__(16) char ldsbuf[106496 + 16384];
  short* ylds = (short*)ldsbuf;                  // [jl][nt][kk][512 shorts]
  float* red  = (float*)(ldsbuf + 106496);       // [wq][ii][jl][64 t]

  const int tid  = threadIdx.x;
  const int lane = tid & 63;
  const int wid  = tid >> 6;         // 0..7
  const int wq   = wid & 3;
  const int jh   = wid >> 2;
  const int ibase = (blockIdx.x >> 4) * 4;
  const int j0    = (blockIdx.x & 15) * 4;

  // Stage 4 j-slices: 4*1664 = 6656 16B-units, 512 thr -> 13 iters each.
  {
    const short* src = ypT + (size_t)j0 * YCH_PER_J * 8;
    for (int c = tid; c < 4 * YCH_PER_J; c += 512) {
      glds16(src + (size_t)c * 8, ldsbuf + c * 16);
    }
  }
  __syncthreads();

  for (int ii = 0; ii < 4; ii++) {
    const int i = ibase + ii;

    floatx16 acc[2][2][2];           // [jjj][m][nt]
#pragma unroll
    for (int jjj = 0; jjj < 2; jjj++)
#pragma unroll
      for (int m = 0; m < 2; m++)
#pragma unroll
        for (int nt = 0; nt < 2; nt++)
#pragma unroll
          for (int r = 0; r < 16; r++) acc[jjj][m][nt][r] = 0.f;

    const short* a0base = xpT + ((size_t)((i * 8 + wq * 2 + 0) * NKK) * 512) + lane * 8;
    const short* a1base = xpT + ((size_t)((i * 8 + wq * 2 + 1) * NKK) * 512) + lane * 8;

#pragma unroll
    for (int kk = 0; kk < NKK; kk++) {
      const short8 a0 = *(const short8*)(a0base + kk * 512);
      const short8 a1 = *(const short8*)(a1base + kk * 512);
#pragma unroll
      for (int jjj = 0; jjj < 2; jjj++) {
#pragma unroll
        for (int nt = 0; nt < 2; nt++) {
          const int jl = jh * 2 + jjj;
          const short8 bf = *(const short8*)(ylds + ((size_t)((jl * 2 + nt) * NKK + kk)) * 512 + lane * 8);
          acc[jjj][0][nt] = __builtin_amdgcn_mfma_f32_32x32x16_bf16(a0, bf, acc[jjj][0][nt], 0, 0, 0);
          acc[jjj][1][nt] = __builtin_amdgcn_mfma_f32_32x32x16_bf16(a1, bf, acc[jjj][1][nt], 0, 0, 0);
        }
      }
    }

    // Per-wave max over its 64 L-rows per column t (C layout: col = lane&31).
#pragma unroll
    for (int jjj = 0; jjj < 2; jjj++) {
#pragma unroll
      for (int nt = 0; nt < 2; nt++) {
        float v = acc[jjj][0][nt][0];
#pragma unroll
        for (int m = 0; m < 2; m++)
#pragma unroll
          for (int r = 0; r < 16; r++) v = fmaxf(v, acc[jjj][m][nt][r]);
        v = fmaxf(v, __shfl_xor(v, 32, 64));
        if (lane < 32) {
          const int jl = jh * 2 + jjj;
          red[((wq * 4 + ii) * 4 + jl) * 64 + nt * 32 + lane] = v;
        }
      }
    }
  }
  __syncthreads();

  // Final: 16 (ii,jl) combos x 64 t; each wave handles 2 combos.
#pragma unroll
  for (int w2 = 0; w2 < 2; w2++) {
    const int combo = wid * 2 + w2;
    const int ii = combo >> 2;
    const int jl = combo & 3;
    const int t  = lane;
    float v = red[((0 * 4 + ii) * 4 + jl) * 64 + t];
    v = fmaxf(v, red[((1 * 4 + ii) * 4 + jl) * 64 + t]);
    v = fmaxf(v, red[((2 * 4 + ii) * 4 + jl) * 64 + t]);
    v = fmaxf(v, red[((3 * 4 + ii) * 4 + jl) * 64 + t]);
    v += __shfl_xor(v, 1, 64);
    v += __shfl_xor(v, 2, 64);
    v += __shfl_xor(v, 4, 64);
    v += __shfl_xor(v, 8, 64);
    v += __shfl_xor(v, 16, 64);
    v += __shfl_xor(v, 32, 64);
    if (t == 0) S[(ibase + ii) * BB + j0 + jl] = v * (1.0f / 64.0f);
  }
}

extern "C" void kernel_launch(void* const* d_in, const int* in_sizes, int n_in,
                              void* d_out, int out_size, void* d_ws, size_t ws_size,
                              hipStream_t stream) {
  const float* x = (const float*)d_in[0];   // 64*256*512
  const float* y = (const float*)d_in[1];   // 64*64*512
  const float* W = (const float*)d_in[2];   // 200*512
  const float* b = (const float*)d_in[3];   // 200
  float* S = (float*)d_out;                 // 64*64

  char* ws = (char*)d_ws;
  short* Wb = (short*)ws;                   // 208*512*2 = 212,992 B
  short* pT = (short*)(ws + 262144);        // 8320 chunks * 1024 B = 8,519,680 B
  short* ypT = pT + (size_t)6656 * 512;     // y starts at chunk 6656

  wcvt_kernel<<<416, 256, 0, stream>>>(W, Wb);
  proj_kernel<<<320, 256, 0, stream>>>(x, y, Wb, b, pT);
  pair_kernel<<<256, 512, 0, stream>>>(pT, ypT, S);
}